// Round 14
// baseline (172.554 us; speedup 1.0000x reference)
//
#include <hip/hip_runtime.h>
#include <math.h>

#define BB 512
#define DD 512
#define KK 93431
#define KPAD 93440

#define S_SCALEf 64.0f
#define COS_Mf   0.87758256189037276f   /* cos(0.5) */
#define SIN_Mf   0.47942553860420301f   /* sin(0.5) */
#define THRESHf (-0.87758256189037276f) /* cos(pi-0.5) */
#define MMf      0.23971276930210151f   /* sin(pi-0.5)*0.5 */
#define EPSf     0.1f
#define MFIXf    65.0f

typedef __bf16 bf16x8 __attribute__((ext_vector_type(8)));
typedef float  f32x4  __attribute__((ext_vector_type(4)));
typedef unsigned short ushort8 __attribute__((ext_vector_type(8)));

__device__ __forceinline__ unsigned short f2bf(float f) {
    union { float f; unsigned u; } v; v.f = f;
    unsigned r = v.u + 0x7FFFu + ((v.u >> 16) & 1u);   // RNE
    return (unsigned short)(r >> 16);
}

__device__ __forceinline__ void gload16(const void* g, void* l) {
    __builtin_amdgcn_global_load_lds(
        (const __attribute__((address_space(1))) unsigned int*)g,
        (__attribute__((address_space(3))) unsigned int*)l, 16, 0, 0);
}

// ---------------- kernel 1: row-normalize x -> xn (f32) + xnb (bf16) ----------------
__global__ void rownorm_k(const float* __restrict__ x, float* __restrict__ xn,
                          unsigned short* __restrict__ xnb) {
    int b = blockIdx.x;
    int t = threadIdx.x; // 256
    float v0 = x[b * DD + t];
    float v1 = x[b * DD + t + 256];
    float ss = v0 * v0 + v1 * v1;
    for (int off = 32; off; off >>= 1) ss += __shfl_down(ss, off);
    __shared__ float wred[4];
    __shared__ float s_inv;
    if ((t & 63) == 0) wred[t >> 6] = ss;
    __syncthreads();
    if (t == 0) s_inv = rsqrtf(wred[0] + wred[1] + wred[2] + wred[3]);
    __syncthreads();
    float inv = s_inv;
    float a0 = v0 * inv, a1 = v1 * inv;
    xn[b * DD + t]        = a0;
    xn[b * DD + t + 256]  = a1;
    xnb[b * DD + t]       = f2bf(a0);
    xnb[b * DD + t + 256] = f2bf(a1);
}

// ------------- kernel 2: transpose+convert kernel matrix, partial column sumsq -------
__global__ __launch_bounds__(256) void tcvt_k(const float* __restrict__ ker,
                                              unsigned short* __restrict__ kerbt,
                                              float* __restrict__ ssq) {
    __shared__ float tile[64][65];
    __shared__ float sp[256];
    int t = threadIdx.x;
    int c0 = blockIdx.x * 64;
    int d0 = blockIdx.y * 64;
    int lc = t & 63;
    int dq = t >> 6;
    int gc = c0 + lc;
    bool valid = gc < KK;
    float ss = 0.f;
#pragma unroll
    for (int i = 0; i < 16; ++i) {
        int d = dq + i * 4;
        float v = valid ? ker[(size_t)(d0 + d) * KK + gc] : 0.f;
        tile[d][lc] = v;
        ss = fmaf(v, v, ss);
    }
    sp[t] = ss;
    __syncthreads();
    if (t < 64 && (c0 + t) < KK) {
        float tot = sp[t] + sp[t + 64] + sp[t + 128] + sp[t + 192];
        atomicAdd(&ssq[c0 + t], tot);
    }
#pragma unroll
    for (int j = 0; j < 2; ++j) {
        int l = t + 256 * j;
        int c = l >> 3;
        int dc = l & 7;
        ushort8 o;
#pragma unroll
        for (int e = 0; e < 8; ++e) o[e] = f2bf(tile[dc * 8 + e][c]);
        *reinterpret_cast<ushort8*>(&kerbt[(size_t)(c0 + c) * DD + d0 + dc * 8]) = o;
    }
}

// ---------------- kernel 3: target logits (label columns, fp32) ----------------
__global__ void target_k(const float* __restrict__ xn, const float* __restrict__ ker,
                         const float* __restrict__ ssq, const int* __restrict__ label,
                         float* __restrict__ tl) {
    int b = blockIdx.x;
    int lane = threadIdx.x; // 64
    int col = label[b];
    float acc = 0.f;
#pragma unroll
    for (int d = lane; d < DD; d += 64)
        acc = fmaf(xn[b * DD + d], ker[(size_t)d * KK + col], acc);
    for (int off = 32; off; off >>= 1) acc += __shfl_down(acc, off);
    if (lane == 0) {
        float c = acc * rsqrtf(ssq[col]);
        c = fminf(1.f, fmaxf(-1.f, c));
        tl[b] = c;
    }
}

// ------- kernel 4: scalars (t_new, cos_theta_m, final target) + ssq pad fix -------
__global__ void scalar_k(const float* __restrict__ tl, const float* __restrict__ t_in,
                         float* __restrict__ ctm, float* __restrict__ ftl,
                         float* __restrict__ tnew, float* __restrict__ ssq) {
    int t = threadIdx.x; // 512
    float v = tl[t];
    __shared__ float red[8];
    __shared__ float s_tn;
    float s = v;
    for (int off = 32; off; off >>= 1) s += __shfl_down(s, off);
    if ((t & 63) == 0) red[t >> 6] = s;
    __syncthreads();
    if (t == 0) {
        float tot = 0.f;
        for (int i = 0; i < 8; ++i) tot += red[i];
        s_tn = (tot / 512.0f) * 0.01f + 0.99f * t_in[0];
        tnew[0] = s_tn;
    }
    __syncthreads();
    float st = sqrtf(fmaxf(0.f, 1.f - v * v));
    float cm = v * COS_Mf - st * SIN_Mf;
    ctm[t] = cm;
    ftl[t] = (v > THRESHf) ? cm : (v - MMf);
    if (t < KPAD - KK) ssq[KK + t] = 1.f;   // pad cols: kerbt rows are 0 -> logit 0
}

// ---- kernel 5: 128x128 tile, BK=32, 256 threads (4 waves of 64x64), 3 blocks/CU.
//      TRIPLE-buffered, counted vmcnt(4): tile kt+2 stays in flight across the
//      barrier (loads span barriers — the T4 lever).  LDS 3x(8+8)KB + 2.5KB = 50.6KB.
#define TMt 128
#define TNt 128
#define BKt 32
#define NWG ((KPAD / TNt) * (BB / TMt))   /* 730 * 4 = 2920 */

__global__ __launch_bounds__(256, 4) void gemm_k(
    const unsigned short* __restrict__ xnb,    // [512][512] bf16 row-major
    const unsigned short* __restrict__ kerbt,  // [KPAD][512] bf16 row-major
    const float* __restrict__ ssq,
    const int* __restrict__ label,
    const float* __restrict__ ctm, const float* __restrict__ ftl,
    const float* __restrict__ tnew,
    float* __restrict__ gse, float* __restrict__ gsl)
{
    __shared__ __align__(16) unsigned short As[3][TMt * BKt];  // 3 x 8 KB
    __shared__ __align__(16) unsigned short Bs[3][TNt * BKt];  // 3 x 8 KB
    __shared__ float se_s[TMt], sl_s[TMt], ctm_s[TMt], ftl_s[TMt];
    __shared__ int   lbl_s[TMt];

    // bijective XCD swizzle (2920 % 8 == 0); row-block-inner decomposition
    int wg = blockIdx.x;
    int id = (wg & 7) * (NWG / 8) + (wg >> 3);
    int by = id & 3;                   // 4 row-blocks of a col-tile adjacent (XCD L2)
    int bx = id >> 2;
    int row0 = by * TMt;
    int col0 = bx * TNt;

    const int t = threadIdx.x;         // 256
    const int lane = t & 63;
    const int w = t >> 6;
    const int wm = w >> 1;             // 0..1  (64-row slice)
    const int wn = w & 1;              // 0..1  (64-col slice)
    const int cp0 = lane & 15;
    const int kq = lane >> 4;          // 0..3 (8-bf16 k-chunk within BK=32)

    if (t < TMt) {
        se_s[t] = 0.f; sl_s[t] = 0.f;
        int r = row0 + t;
        ctm_s[t] = ctm[r]; ftl_s[t] = ftl[r]; lbl_s[t] = label[r];
    }
    const float tn = tnew[0];

    // prologue ssq loads (oldest in vmcnt order; any counted wait drains them)
    float sq4[4];
#pragma unroll
    for (int fc = 0; fc < 4; ++fc)
        sq4[fc] = ssq[col0 + wn * 64 + fc * 16 + cp0];

    // ---- staging: tile = 128 rows x 32 k = 512 chunks of 16B; 2 A + 2 B per thread.
    //      chunk l: row r = l>>2, slot s = l&3; source k-chunk kc = s ^ ((r>>1)&3).
#define STAGE(ktv, bi)                                                         \
    {                                                                          \
        _Pragma("unroll")                                                      \
        for (int j = 0; j < 2; ++j) {                                          \
            const int l = t + 256 * j;                                         \
            const int r = l >> 2, s = l & 3;                                   \
            const int kc = s ^ ((r >> 1) & 3);                                 \
            gload16(&xnb[(size_t)(row0 + r) * DD + (ktv) * BKt + kc * 8],      \
                    (void*)&As[bi][l * 8]);                                    \
        }                                                                      \
        _Pragma("unroll")                                                      \
        for (int j = 0; j < 2; ++j) {                                          \
            const int l = t + 256 * j;                                         \
            const int r = l >> 2, s = l & 3;                                   \
            const int kc = s ^ ((r >> 1) & 3);                                 \
            gload16(&kerbt[(size_t)(col0 + r) * DD + (ktv) * BKt + kc * 8],    \
                    (void*)&Bs[bi][l * 8]);                                    \
        }                                                                      \
    }

    f32x4 acc[4][4];
#pragma unroll
    for (int fm = 0; fm < 4; ++fm)
#pragma unroll
        for (int fc = 0; fc < 4; ++fc) acc[fm][fc] = (f32x4)0.f;

    // ---- prologue: stage tiles 0 and 1; wait tile 0 only (tile 1 stays in flight) ----
    STAGE(0, 0);
    STAGE(1, 1);
    __builtin_amdgcn_sched_barrier(0);
    asm volatile("s_waitcnt vmcnt(4)" ::: "memory");
    __builtin_amdgcn_s_barrier();

    // ---- main loop: 16 k-steps, loads span barriers (counted vmcnt) ----
#pragma unroll
    for (int kt = 0; kt < 16; ++kt) {
        const int bi = kt % 3;
        if (kt + 2 < 16) STAGE(kt + 2, (kt + 2) % 3);  // into buffer freed at kt-1
        const char* Ap = (const char*)&As[bi][0];
        const char* Bp = (const char*)&Bs[bi][0];

        bf16x8 bfr[4];
#pragma unroll
        for (int fc = 0; fc < 4; ++fc) {
            const int ct = wn * 64 + fc * 16 + cp0;
            bfr[fc] = *reinterpret_cast<const bf16x8*>(
                Bp + ct * 64 + ((kq ^ ((ct >> 1) & 3)) * 16));
        }
        __builtin_amdgcn_s_setprio(1);
#pragma unroll
        for (int fm = 0; fm < 4; ++fm) {
            const int rt = wm * 64 + fm * 16 + cp0;
            bf16x8 af = *reinterpret_cast<const bf16x8*>(
                Ap + rt * 64 + ((kq ^ ((rt >> 1) & 3)) * 16));
#pragma unroll
            for (int fc = 0; fc < 4; ++fc)
                acc[fm][fc] = __builtin_amdgcn_mfma_f32_16x16x32_bf16(
                    af, bfr[fc], acc[fm][fc], 0, 0, 0);
        }
        __builtin_amdgcn_s_setprio(0);

        // wait tile kt+1 landed; tile kt+2 (4 loads) stays in flight
        if (kt + 1 < 16) {
            __builtin_amdgcn_sched_barrier(0);
            if (kt + 2 < 16)
                asm volatile("s_waitcnt vmcnt(4)" ::: "memory");
            else
                asm volatile("s_waitcnt vmcnt(0)" ::: "memory");
            __builtin_amdgcn_s_barrier();
        }
    }
#undef STAGE

    // ---- fused CurricularFace epilogue (once per block, full-K acc) ----
    float inv4[4];
#pragma unroll
    for (int fc = 0; fc < 4; ++fc) inv4[fc] = rsqrtf(sq4[fc]);

#pragma unroll
    for (int fm = 0; fm < 4; ++fm) {
#pragma unroll
        for (int reg = 0; reg < 4; ++reg) {
            const int rt = wm * 64 + fm * 16 + (kq << 2) + reg;  // block-local row
            float cm = ctm_s[rt], ft = ftl_s[rt];
            const int rel = lbl_s[rt] - (col0 + wn * 64 + cp0);
            float se = 0.f, sl = 0.f;
#pragma unroll
            for (int fc = 0; fc < 4; ++fc) {
                float c = acc[fm][fc][reg] * inv4[fc];
                c = fminf(1.f, fmaxf(-1.f, c));
                float v = (c > cm) ? c * (tn + c) : c;
                if (rel == fc * 16) v = ft;
                float lg = S_SCALEf * v;
                se += __expf(lg - MFIXf);    // pad cols: cos=0 -> exp(-65)~0, lg=0
                sl += lg;
            }
#pragma unroll
            for (int off = 8; off; off >>= 1) {
                se += __shfl_down(se, off, 16);
                sl += __shfl_down(sl, off, 16);
            }
            if (cp0 == 0) {
                atomicAdd(&se_s[rt], se);
                atomicAdd(&sl_s[rt], sl);
            }
        }
    }
    __syncthreads();
    if (t < TMt) {
        atomicAdd(&gse[row0 + t], se_s[t]);
        atomicAdd(&gsl[row0 + t], sl_s[t]);
    }
}

// ---------------- kernel 6: final loss ----------------
__global__ void loss_k(const float* __restrict__ gse, const float* __restrict__ gsl,
                       const float* __restrict__ ftl, float* __restrict__ out) {
    int t = threadIdx.x; // 512
    float lse = MFIXf + logf(gse[t]);
    float lbl_logit = S_SCALEf * ftl[t];
    float nll = (1.f - EPSf) * (lbl_logit - lse)
              + (EPSf / (float)KK) * (gsl[t] - (float)KK * lse);
    __shared__ float red[8];
    float s = nll;
    for (int off = 32; off; off >>= 1) s += __shfl_down(s, off);
    if ((t & 63) == 0) red[t >> 6] = s;
    __syncthreads();
    if (t == 0) {
        float tot = 0.f;
        for (int i = 0; i < 8; ++i) tot += red[i];
        out[0] = -(tot / 512.0f);
    }
}

extern "C" void kernel_launch(void* const* d_in, const int* in_sizes, int n_in,
                              void* d_out, int out_size, void* d_ws, size_t ws_size,
                              hipStream_t stream) {
    const float* x     = (const float*)d_in[0];
    const int*   label = (const int*)d_in[1];
    const float* ker   = (const float*)d_in[2];
    const float* t_in  = (const float*)d_in[3];
    float* out = (float*)d_out;

    float* ws   = (float*)d_ws;
    float* xn   = ws;                 // 262144 f32
    float* ssq  = xn + 262144;        // KPAD
    float* gse  = ssq + KPAD;         // 512
    float* gsl  = gse + 512;          // 512
    float* tl   = gsl + 512;          // 512
    float* ctm  = tl + 512;           // 512
    float* ftl  = ctm + 512;          // 512
    float* tnew = ftl + 512;          // 64
    unsigned short* xnb   = (unsigned short*)(tnew + 64);    // 262144 bf16
    unsigned short* kerbt = xnb + 262144;                    // KPAD*512 bf16

    hipMemsetAsync(ssq, 0, (KPAD + 1024) * sizeof(float), stream);

    rownorm_k<<<BB, 256, 0, stream>>>(x, xn, xnb);
    tcvt_k<<<dim3(KPAD / 64, DD / 64), 256, 0, stream>>>(ker, kerbt, ssq);
    target_k<<<BB, 64, 0, stream>>>(xn, ker, ssq, label, tl);
    scalar_k<<<1, 512, 0, stream>>>(tl, t_in, ctm, ftl, tnew, ssq);
    gemm_k<<<NWG, 256, 0, stream>>>(xnb, kerbt, ssq, label, ctm, ftl, tnew, gse, gsl);
    loss_k<<<1, 512, 0, stream>>>(gse, gsl, ftl, out);
}

// Round 15
// 125.863 us; speedup vs baseline: 1.3710x; 1.3710x over previous
//
#include <hip/hip_runtime.h>
#include <math.h>

#define BB 512
#define DD 512
#define KK 93431
#define KPAD 93440

#define S_SCALEf 64.0f
#define COS_Mf   0.87758256189037276f   /* cos(0.5) */
#define SIN_Mf   0.47942553860420301f   /* sin(0.5) */
#define THRESHf (-0.87758256189037276f) /* cos(pi-0.5) */
#define MMf      0.23971276930210151f   /* sin(pi-0.5)*0.5 */
#define EPSf     0.1f
#define MFIXf    65.0f

#define KSCALE 64.0f     /* kernel pre-scale before fp8 quantization */
#define XSCALE 16.0f     /* xn pre-scale before fp8 quantization */
#define INV_KX (1.0f / (KSCALE * XSCALE))

typedef float f32x4 __attribute__((ext_vector_type(4)));
typedef long  l64x2 __attribute__((ext_vector_type(2)));

__device__ __forceinline__ unsigned short f2bf(float f) {
    union { float f; unsigned u; } v; v.f = f;
    unsigned r = v.u + 0x7FFFu + ((v.u >> 16) & 1u);
    return (unsigned short)(r >> 16);
}

__device__ __forceinline__ unsigned pack4_fp8(float a, float b, float c, float d) {
    unsigned v = 0;
    v = __builtin_amdgcn_cvt_pk_fp8_f32(a, b, v, false);  // bytes 0-1
    v = __builtin_amdgcn_cvt_pk_fp8_f32(c, d, v, true);   // bytes 2-3
    return v;
}

__device__ __forceinline__ void gload16(const void* g, void* l) {
    __builtin_amdgcn_global_load_lds(
        (const __attribute__((address_space(1))) unsigned int*)g,
        (__attribute__((address_space(3))) unsigned int*)l, 16, 0, 0);
}

// ---- kernel 1: row-normalize x -> xn (f32) + xnf8 (fp8 x16, chunk-interleaved) ----
// fp8 row layout (per 64B k-tile): slot s (16B) holds k-chunks (s, s+4); chunk = 8 fp8.
__global__ void rownorm_k(const float* __restrict__ x, float* __restrict__ xn,
                          unsigned char* __restrict__ xnf8) {
    int b = blockIdx.x;
    int t = threadIdx.x; // 256
    float v0 = x[b * DD + t];
    float v1 = x[b * DD + t + 256];
    float ss = v0 * v0 + v1 * v1;
    for (int off = 32; off; off >>= 1) ss += __shfl_down(ss, off);
    __shared__ float wred[4];
    __shared__ float s_inv;
    __shared__ float rbF[512];
    if ((t & 63) == 0) wred[t >> 6] = ss;
    __syncthreads();
    if (t == 0) s_inv = rsqrtf(wred[0] + wred[1] + wred[2] + wred[3]);
    __syncthreads();
    float inv = s_inv;
    float a0 = v0 * inv, a1 = v1 * inv;
    xn[b * DD + t]       = a0;
    xn[b * DD + t + 256] = a1;
    rbF[t]       = a0;
    rbF[t + 256] = a1;
    __syncthreads();
    if (t < 64) {
        int kt = t >> 3, ch = t & 7;      // k-tile 0..7, chunk 0..7
        float v[8];
#pragma unroll
        for (int e = 0; e < 8; ++e) v[e] = XSCALE * rbF[kt * 64 + ch * 8 + e];
        unsigned w0 = pack4_fp8(v[0], v[1], v[2], v[3]);
        unsigned w1 = pack4_fp8(v[4], v[5], v[6], v[7]);
        uint2 o = {w0, w1};
        int off = (ch < 4) ? ch * 16 : (ch - 4) * 16 + 8;
        *reinterpret_cast<uint2*>(&xnf8[(size_t)b * DD + kt * 64 + off]) = o;
    }
}

// ---- kernel 2: transpose kernel matrix -> fp8 (x64, chunk-interleaved) + col sumsq ----
__global__ __launch_bounds__(256) void tcvt_k(const float* __restrict__ ker,
                                              unsigned char* __restrict__ kerf8,
                                              float* __restrict__ ssq) {
    __shared__ float tile[64][65];
    __shared__ float sp[256];
    int t = threadIdx.x;
    int c0 = blockIdx.x * 64;
    int kt = blockIdx.y;                // k-tile; d0 = kt*64
    int d0 = kt * 64;
    int lc = t & 63;
    int dq = t >> 6;
    int gc = c0 + lc;
    bool valid = gc < KK;
    float ss = 0.f;
#pragma unroll
    for (int i = 0; i < 16; ++i) {
        int d = dq + i * 4;
        float v = valid ? ker[(size_t)(d0 + d) * KK + gc] : 0.f;
        tile[d][lc] = v;
        ss = fmaf(v, v, ss);
    }
    sp[t] = ss;
    __syncthreads();
    if (t < 64 && (c0 + t) < KK) {
        float tot = sp[t] + sp[t + 64] + sp[t + 128] + sp[t + 192];
        atomicAdd(&ssq[c0 + t], tot);
    }
    // write fp8 x KSCALE, chunk-interleaved
#pragma unroll
    for (int j = 0; j < 2; ++j) {
        int l = t + 256 * j;            // 0..511
        int c = l >> 3;                 // col 0..63
        int ch = l & 7;                 // chunk (k = ch*8..+7 within tile)
        float v[8];
#pragma unroll
        for (int e = 0; e < 8; ++e) v[e] = KSCALE * tile[ch * 8 + e][c];
        unsigned w0 = pack4_fp8(v[0], v[1], v[2], v[3]);
        unsigned w1 = pack4_fp8(v[4], v[5], v[6], v[7]);
        uint2 o = {w0, w1};
        int off = (ch < 4) ? ch * 16 : (ch - 4) * 16 + 8;
        *reinterpret_cast<uint2*>(&kerf8[(size_t)(c0 + c) * DD + kt * 64 + off]) = o;
    }
}

// ---------------- kernel 3: target logits (label columns, fp32 — exact) ----------------
__global__ void target_k(const float* __restrict__ xn, const float* __restrict__ ker,
                         const float* __restrict__ ssq, const int* __restrict__ label,
                         float* __restrict__ tl) {
    int b = blockIdx.x;
    int lane = threadIdx.x; // 64
    int col = label[b];
    float acc = 0.f;
#pragma unroll
    for (int d = lane; d < DD; d += 64)
        acc = fmaf(xn[b * DD + d], ker[(size_t)d * KK + col], acc);
    for (int off = 32; off; off >>= 1) acc += __shfl_down(acc, off);
    if (lane == 0) {
        float c = acc * rsqrtf(ssq[col]);
        c = fminf(1.f, fmaxf(-1.f, c));
        tl[b] = c;
    }
}

// ------- kernel 4: scalars (t_new, cos_theta_m, final target) + ssq pad fix -------
__global__ void scalar_k(const float* __restrict__ tl, const float* __restrict__ t_in,
                         float* __restrict__ ctm, float* __restrict__ ftl,
                         float* __restrict__ tnew, float* __restrict__ ssq) {
    int t = threadIdx.x; // 512
    float v = tl[t];
    __shared__ float red[8];
    __shared__ float s_tn;
    float s = v;
    for (int off = 32; off; off >>= 1) s += __shfl_down(s, off);
    if ((t & 63) == 0) red[t >> 6] = s;
    __syncthreads();
    if (t == 0) {
        float tot = 0.f;
        for (int i = 0; i < 8; ++i) tot += red[i];
        s_tn = (tot / 512.0f) * 0.01f + 0.99f * t_in[0];
        tnew[0] = s_tn;
    }
    __syncthreads();
    float st = sqrtf(fmaxf(0.f, 1.f - v * v));
    float cm = v * COS_Mf - st * SIN_Mf;
    ctm[t] = cm;
    ftl[t] = (v > THRESHf) ? cm : (v - MMf);
    if (t < KPAD - KK) ssq[KK + t] = 1.f;   // pad cols: kerf8 rows are 0 -> logit 0
}

// ---- kernel 5: fp8 GEMM.  128x128 tile, BK=64 (fp8), 256 thr (4 waves of 64x64),
//      4 blocks/CU (LDS 2x(8+8)KB + 2.5KB = 34.5KB).  r13-proven 1-barrier 2-phase.
//      One b128 LDS read per fragment-pair covers BOTH K=32 MFMA chunks (interleave).
#define TMt 128
#define TNt 128
#define NWG ((KPAD / TNt) * (BB / TMt))   /* 730 * 4 = 2920 */

__global__ __launch_bounds__(256, 4) void gemm_k(
    const unsigned char* __restrict__ xnf8,    // [512][512] fp8 (x16), interleaved
    const unsigned char* __restrict__ kerf8,   // [KPAD][512] fp8 (x64), interleaved
    const float* __restrict__ ssq,
    const int* __restrict__ label,
    const float* __restrict__ ctm, const float* __restrict__ ftl,
    const float* __restrict__ tnew,
    float* __restrict__ gse, float* __restrict__ gsl)
{
    __shared__ __align__(16) unsigned char As[2][TMt * 64];  // 2 x 8 KB
    __shared__ __align__(16) unsigned char Bs[2][TNt * 64];  // 2 x 8 KB
    __shared__ float se_s[TMt], sl_s[TMt], ctm_s[TMt], ftl_s[TMt];
    __shared__ int   lbl_s[TMt];

    // bijective XCD swizzle (2920 % 8 == 0); row-block-inner decomposition
    int wg = blockIdx.x;
    int id = (wg & 7) * (NWG / 8) + (wg >> 3);
    int by = id & 3;
    int bx = id >> 2;
    int row0 = by * TMt;
    int col0 = bx * TNt;

    const int t = threadIdx.x;         // 256
    const int lane = t & 63;
    const int w = t >> 6;
    const int wm = w >> 1;             // 0..1 (64-row slice)
    const int wn = w & 1;              // 0..1 (64-col slice)
    const int cp0 = lane & 15;
    const int kq = lane >> 4;          // 0..3 (8-fp8 chunk within K=32)

    if (t < TMt) {
        se_s[t] = 0.f; sl_s[t] = 0.f;
        int r = row0 + t;
        ctm_s[t] = ctm[r]; ftl_s[t] = ftl[r]; lbl_s[t] = label[r];
    }
    const float tn = tnew[0];

    float sq4[4];
#pragma unroll
    for (int fc = 0; fc < 4; ++fc)
        sq4[fc] = ssq[col0 + wn * 64 + fc * 16 + cp0];

    // ---- staging: tile = 128 rows x 64B = 512 chunks of 16B; 2 A + 2 B per thread.
    //      chunk l: row r = l>>2, slot s = l&3; source slot ss = s ^ ((r>>1)&3).
#define STAGE(ktv, bi)                                                         \
    {                                                                          \
        _Pragma("unroll")                                                      \
        for (int j = 0; j < 2; ++j) {                                          \
            const int l = t + 256 * j;                                         \
            const int r = l >> 2, s = l & 3;                                   \
            const int ss2 = s ^ ((r >> 1) & 3);                                \
            gload16(&xnf8[(size_t)(row0 + r) * DD + (ktv) * 64 + ss2 * 16],    \
                    (void*)&As[bi][l * 16]);                                   \
        }                                                                      \
        _Pragma("unroll")                                                      \
        for (int j = 0; j < 2; ++j) {                                          \
            const int l = t + 256 * j;                                         \
            const int r = l >> 2, s = l & 3;                                   \
            const int ss2 = s ^ ((r >> 1) & 3);                                \
            gload16(&kerf8[(size_t)(col0 + r) * DD + (ktv) * 64 + ss2 * 16],   \
                    (void*)&Bs[bi][l * 16]);                                   \
        }                                                                      \
    }

    f32x4 acc[4][4];
#pragma unroll
    for (int fm = 0; fm < 4; ++fm)
#pragma unroll
        for (int fc = 0; fc < 4; ++fc) acc[fm][fc] = (f32x4)0.f;

    // ---- prologue: stage k-tile 0 -> buf 0 ----
    STAGE(0, 0);
    __builtin_amdgcn_sched_barrier(0);
    asm volatile("s_waitcnt vmcnt(0)" ::: "memory");
    __builtin_amdgcn_s_barrier();

    // ---- main loop: 8 k-steps (BK=64), stage-early, ONE barrier per step ----
#pragma unroll
    for (int kt = 0; kt < 8; ++kt) {
        const int bi = kt & 1;
        if (kt < 7) STAGE(kt + 1, bi ^ 1);
        const char* Ap = (const char*)&As[bi][0];
        const char* Bp = (const char*)&Bs[bi][0];

        // B fragment pairs: [0] = k 0..31 chunk, [1] = k 32..63 chunk
        l64x2 bv[4];
#pragma unroll
        for (int fc = 0; fc < 4; ++fc) {
            const int ct = wn * 64 + fc * 16 + cp0;
            bv[fc] = *reinterpret_cast<const l64x2*>(
                Bp + ct * 64 + ((kq ^ ((ct >> 1) & 3)) * 16));
        }
        __builtin_amdgcn_s_setprio(1);
#pragma unroll
        for (int fm = 0; fm < 4; ++fm) {
            const int rt = wm * 64 + fm * 16 + cp0;
            l64x2 av = *reinterpret_cast<const l64x2*>(
                Ap + rt * 64 + ((kq ^ ((rt >> 1) & 3)) * 16));
#pragma unroll
            for (int fc = 0; fc < 4; ++fc) {
                acc[fm][fc] = __builtin_amdgcn_mfma_f32_16x16x32_fp8_fp8(
                    av[0], bv[fc][0], acc[fm][fc], 0, 0, 0);
                acc[fm][fc] = __builtin_amdgcn_mfma_f32_16x16x32_fp8_fp8(
                    av[1], bv[fc][1], acc[fm][fc], 0, 0, 0);
            }
        }
        __builtin_amdgcn_s_setprio(0);

        __builtin_amdgcn_sched_barrier(0);
        asm volatile("s_waitcnt vmcnt(0)" ::: "memory");
        __builtin_amdgcn_s_barrier();
    }
#undef STAGE

    // ---- fused CurricularFace epilogue (scale-fold 1/(KSCALE*XSCALE)) ----
    float inv4[4];
#pragma unroll
    for (int fc = 0; fc < 4; ++fc) inv4[fc] = rsqrtf(sq4[fc]) * INV_KX;

#pragma unroll
    for (int fm = 0; fm < 4; ++fm) {
#pragma unroll
        for (int reg = 0; reg < 4; ++reg) {
            const int rt = wm * 64 + fm * 16 + (kq << 2) + reg;
            float cm = ctm_s[rt], ft = ftl_s[rt];
            const int rel = lbl_s[rt] - (col0 + wn * 64 + cp0);
            float se = 0.f, sl = 0.f;
#pragma unroll
            for (int fc = 0; fc < 4; ++fc) {
                float c = acc[fm][fc][reg] * inv4[fc];
                c = fminf(1.f, fmaxf(-1.f, c));
                float v = (c > cm) ? c * (tn + c) : c;
                if (rel == fc * 16) v = ft;
                float lg = S_SCALEf * v;
                se += __expf(lg - MFIXf);    // pad cols: cos=0 -> exp(-65)~0, lg=0
                sl += lg;
            }
#pragma unroll
            for (int off = 8; off; off >>= 1) {
                se += __shfl_down(se, off, 16);
                sl += __shfl_down(sl, off, 16);
            }
            if (cp0 == 0) {
                atomicAdd(&se_s[rt], se);
                atomicAdd(&sl_s[rt], sl);
            }
        }
    }
    __syncthreads();
    if (t < TMt) {
        atomicAdd(&gse[row0 + t], se_s[t]);
        atomicAdd(&gsl[row0 + t], sl_s[t]);
    }
}

// ---------------- kernel 6: final loss ----------------
__global__ void loss_k(const float* __restrict__ gse, const float* __restrict__ gsl,
                       const float* __restrict__ ftl, float* __restrict__ out) {
    int t = threadIdx.x; // 512
    float lse = MFIXf + logf(gse[t]);
    float lbl_logit = S_SCALEf * ftl[t];
    float nll = (1.f - EPSf) * (lbl_logit - lse)
              + (EPSf / (float)KK) * (gsl[t] - (float)KK * lse);
    __shared__ float red[8];
    float s = nll;
    for (int off = 32; off; off >>= 1) s += __shfl_down(s, off);
    if ((t & 63) == 0) red[t >> 6] = s;
    __syncthreads();
    if (t == 0) {
        float tot = 0.f;
        for (int i = 0; i < 8; ++i) tot += red[i];
        out[0] = -(tot / 512.0f);
    }
}

extern "C" void kernel_launch(void* const* d_in, const int* in_sizes, int n_in,
                              void* d_out, int out_size, void* d_ws, size_t ws_size,
                              hipStream_t stream) {
    const float* x     = (const float*)d_in[0];
    const int*   label = (const int*)d_in[1];
    const float* ker   = (const float*)d_in[2];
    const float* t_in  = (const float*)d_in[3];
    float* out = (float*)d_out;

    float* ws   = (float*)d_ws;
    float* xn   = ws;                 // 262144 f32
    float* ssq  = xn + 262144;        // KPAD
    float* gse  = ssq + KPAD;         // 512
    float* gsl  = gse + 512;          // 512
    float* tl   = gsl + 512;          // 512
    float* ctm  = tl + 512;           // 512
    float* ftl  = ctm + 512;          // 512
    float* tnew = ftl + 512;          // 64
    unsigned char* xnf8  = (unsigned char*)(tnew + 64);      // 512*512 fp8
    unsigned char* kerf8 = xnf8 + (size_t)512 * 512;         // KPAD*512 fp8

    hipMemsetAsync(ssq, 0, (KPAD + 1024) * sizeof(float), stream);

    rownorm_k<<<BB, 256, 0, stream>>>(x, xn, xnf8);
    tcvt_k<<<dim3(KPAD / 64, DD / 64), 256, 0, stream>>>(ker, kerf8, ssq);
    target_k<<<BB, 64, 0, stream>>>(xn, ker, ssq, label, tl);
    scalar_k<<<1, 512, 0, stream>>>(tl, t_in, ctm, ftl, tnew, ssq);
    gemm_k<<<NWG, 256, 0, stream>>>(xnf8, kerf8, ssq, label, ctm, ftl, tnew, gse, gsl);
    loss_k<<<1, 512, 0, stream>>>(gse, gsl, ftl, out);
}